// Round 1
// 1787.085 us; speedup vs baseline: 1.2570x; 1.2570x over previous
//
#include <hip/hip_runtime.h>

typedef unsigned short u16;
typedef unsigned int u32;
typedef __attribute__((ext_vector_type(8))) short bf16x8;
typedef __attribute__((ext_vector_type(4))) float f32x4;

#define HH 16
#define NN 4096
#define DD 64
#define MM 256

constexpr float NORMALIZER = 0.35355339059327373f; // 64^-0.25
constexpr float HALF_NORM2 = 0.0625f;              // 0.5 * 64^-0.5
constexpr float RATIO      = 0.0625f;              // 256^-0.5
constexpr float EPSF       = 1e-4f;

__device__ inline float bf2f(u16 u) { return __uint_as_float(((u32)u) << 16); }
__device__ inline u16 f2bf(float f) {
    u32 b = __float_as_uint(f);
    u32 r = b + 0x7FFFu + ((b >> 16) & 1u);
    return (u16)(r >> 16);
}
__device__ inline float ldx(const void* p, size_t i, int mode) {
    return mode ? ((const float*)p)[i] : bf2f(((const u16*)p)[i]);
}
__device__ inline u32 encf(float f) {
    u32 b = __float_as_uint(f);
    return (b & 0x80000000u) ? ~b : (b | 0x80000000u);
}
__device__ inline float decf(u32 u) {
    return (u & 0x80000000u) ? __uint_as_float(u ^ 0x80000000u) : __uint_as_float(~u);
}

// load 8 consecutive elements as f32 (handles f32 or bf16 input)
__device__ inline void load8f(const void* p, size_t idx, int mode, float v[8]) {
    if (mode) {
        const float* f = (const float*)p + idx;
        float4 a = *(const float4*)f;
        float4 b = *(const float4*)(f + 4);
        v[0]=a.x; v[1]=a.y; v[2]=a.z; v[3]=a.w;
        v[4]=b.x; v[5]=b.y; v[6]=b.z; v[7]=b.w;
    } else {
        uint4 uu = *(const uint4*)((const u16*)p + idx);
        v[0]=bf2f((u16)uu.x); v[1]=bf2f((u16)(uu.x>>16));
        v[2]=bf2f((u16)uu.y); v[3]=bf2f((u16)(uu.y>>16));
        v[4]=bf2f((u16)uu.z); v[5]=bf2f((u16)(uu.z>>16));
        v[6]=bf2f((u16)uu.w); v[7]=bf2f((u16)(uu.w>>16));
    }
}
// hi/lo bf16 split: v == hi + lo to ~2^-16 relative
__device__ inline void split8(const float v[8], bf16x8& hi, bf16x8& lo) {
#pragma unroll
    for (int j = 0; j < 8; ++j) {
        u16 h = f2bf(v[j]);
        hi[j] = (short)h;
        lo[j] = (short)f2bf(v[j] - bf2f(h));
    }
}

// ---------------- K0: input dtype detection ----------------
__global__ __launch_bounds__(256) void detect_kernel(const u32* __restrict__ q,
                                                     int* __restrict__ mode) {
    __shared__ int cnt;
    if (threadIdx.x == 0) cnt = 0;
    __syncthreads();
    int c = 0;
    for (int i = threadIdx.x; i < 4096; i += 256) {
        u32 w = q[i];
        u32 e = (w >> 23) & 0xffu;
        if ((e >= 103u && e <= 134u) || (w & 0x7fffffffu) == 0u) c++;
    }
    atomicAdd(&cnt, c);
    __syncthreads();
    if (threadIdx.x == 0) *mode = (cnt > 3072) ? 1 : 0;
}

// Shared MFMA core for the feature kernels:
// acc[i][j] = raw (data @ proj^T) for rows n0..n0+63 (i-tiles of 16),
// cols mcol0..mcol0+63 (j-tiles of 16). sq[i] = per-lane partial sum of data^2.
__device__ inline void feat_mfma(const void* data, const void* proj, int mode,
                                 size_t dbase, int mcol0, int lane,
                                 f32x4 (&acc)[4][4], float (&sq)[4]) {
    int r = lane & 15, g = lane >> 4;
#pragma unroll
    for (int i = 0; i < 4; ++i) {
        sq[i] = 0.f;
#pragma unroll
        for (int j = 0; j < 4; ++j)
#pragma unroll
            for (int e = 0; e < 4; ++e) acc[i][j][e] = 0.f;
    }
#pragma unroll
    for (int ks = 0; ks < 2; ++ks) {
        bf16x8 ah[4], al[4], bh[4], bl[4];
#pragma unroll
        for (int i = 0; i < 4; ++i) {
            float v8[8];
            load8f(data, dbase + (size_t)(i * 16 + r) * DD + ks * 32 + g * 8, mode, v8);
            float s = 0.f;
#pragma unroll
            for (int t = 0; t < 8; ++t) s += v8[t] * v8[t];
            sq[i] += s;
            split8(v8, ah[i], al[i]);
        }
#pragma unroll
        for (int j = 0; j < 4; ++j) {
            float v8[8];
            load8f(proj, (size_t)(mcol0 + j * 16 + r) * DD + ks * 32 + g * 8, mode, v8);
            split8(v8, bh[j], bl[j]);
        }
#pragma unroll
        for (int i = 0; i < 4; ++i)
#pragma unroll
            for (int j = 0; j < 4; ++j)
                acc[i][j] = __builtin_amdgcn_mfma_f32_16x16x32_bf16(ah[i], bh[j], acc[i][j], 0, 0, 0);
        if (mode) {  // f32 inputs: add hi*lo + lo*hi cross terms (lo==0 for bf16 inputs)
#pragma unroll
            for (int i = 0; i < 4; ++i)
#pragma unroll
                for (int j = 0; j < 4; ++j) {
                    acc[i][j] = __builtin_amdgcn_mfma_f32_16x16x32_bf16(ah[i], bl[j], acc[i][j], 0, 0, 0);
                    acc[i][j] = __builtin_amdgcn_mfma_f32_16x16x32_bf16(al[i], bh[j], acc[i][j], 0, 0, 0);
                }
        }
    }
}

// ---------------- K1: global max of key logits (MFMA) ----------------
__global__ __launch_bounds__(256) void kmax_kernel(const void* __restrict__ k,
                                                   const void* __restrict__ proj,
                                                   const int* __restrict__ mode_p,
                                                   u32* __restrict__ gmax_enc) {
    int mode = *mode_p;
    int h = blockIdx.x >> 6;
    int n0 = (blockIdx.x & 63) * 64;
    int tid = threadIdx.x, w = tid >> 6, lane = tid & 63;
    f32x4 acc[4][4]; float sq[4];
    feat_mfma(k, proj, mode, (size_t)(h * NN + n0) * DD, w * 64, lane, acc, sq);
    float m = -1e30f;
#pragma unroll
    for (int i = 0; i < 4; ++i)
#pragma unroll
        for (int j = 0; j < 4; ++j)
#pragma unroll
            for (int e = 0; e < 4; ++e) m = fmaxf(m, acc[i][j][e]);
    m *= NORMALIZER;
#pragma unroll
    for (int off = 1; off < 64; off <<= 1) m = fmaxf(m, __shfl_xor(m, off));
    __shared__ float wm[4];
    if (lane == 0) wm[w] = m;
    __syncthreads();
    if (tid == 0)
        atomicMax(gmax_enc, encf(fmaxf(fmaxf(wm[0], wm[1]), fmaxf(wm[2], wm[3]))));
}

// ---------------- K2: key features kp + column sums (MFMA) ----------------
__global__ __launch_bounds__(256) void kp_kernel(const void* __restrict__ k,
                                                 const void* __restrict__ proj,
                                                 const int* __restrict__ mode_p,
                                                 const u32* __restrict__ gmax_enc,
                                                 u16* __restrict__ kp,
                                                 float* __restrict__ ksum) {
    int mode = *mode_p;
    int h = blockIdx.x >> 6;
    int n0 = (blockIdx.x & 63) * 64;
    int tid = threadIdx.x, w = tid >> 6, lane = tid & 63, r = lane & 15, g = lane >> 4;
    __shared__ float diag[64];
    f32x4 acc[4][4]; float sq[4];
    feat_mfma(k, proj, mode, (size_t)(h * NN + n0) * DD, w * 64, lane, acc, sq);
#pragma unroll
    for (int i = 0; i < 4; ++i) {
        float s = sq[i];
        s += __shfl_xor(s, 16); s += __shfl_xor(s, 32);
        sq[i] = s;
    }
    if (w == 0 && lane < 16) {
#pragma unroll
        for (int i = 0; i < 4; ++i) diag[i * 16 + lane] = HALF_NORM2 * sq[i];
    }
    __syncthreads();
    float gmax = decf(*gmax_enc);
    float csum[4] = {0.f, 0.f, 0.f, 0.f};
#pragma unroll
    for (int i = 0; i < 4; ++i)
#pragma unroll
        for (int e = 0; e < 4; ++e) {
            int row = i * 16 + g * 4 + e;
            float dg = diag[row];
#pragma unroll
            for (int j = 0; j < 4; ++j) {
                float val = RATIO * (__expf(NORMALIZER * acc[i][j][e] - dg - gmax) + EPSF);
                kp[(size_t)(h * NN + n0 + row) * MM + w * 64 + j * 16 + r] = f2bf(val);
                csum[j] += val;
            }
        }
#pragma unroll
    for (int j = 0; j < 4; ++j) {
        float s = csum[j];
        s += __shfl_xor(s, 16); s += __shfl_xor(s, 32);
        if (g == 0) atomicAdd(&ksum[h * MM + w * 64 + j * 16 + r], s);
    }
}

// ---------------- K3: query features qp, per-row max (MFMA) ----------------
__global__ __launch_bounds__(256) void qp_kernel(const void* __restrict__ q,
                                                 const void* __restrict__ proj,
                                                 const int* __restrict__ mode_p,
                                                 u16* __restrict__ qp) {
    int mode = *mode_p;
    int h = blockIdx.x >> 6;
    int n0 = (blockIdx.x & 63) * 64;
    int tid = threadIdx.x, w = tid >> 6, lane = tid & 63, r = lane & 15, g = lane >> 4;
    __shared__ float diag[64];
    __shared__ float wmax[4][64];
    f32x4 acc[4][4]; float sq[4];
    feat_mfma(q, proj, mode, (size_t)(h * NN + n0) * DD, w * 64, lane, acc, sq);
#pragma unroll
    for (int i = 0; i < 4; ++i) {
        float s = sq[i];
        s += __shfl_xor(s, 16); s += __shfl_xor(s, 32);
        sq[i] = s;
    }
    if (w == 0 && lane < 16) {
#pragma unroll
        for (int i = 0; i < 4; ++i) diag[i * 16 + lane] = HALF_NORM2 * sq[i];
    }
    // per-row max over this wave's 64 cols (raw, scale later)
#pragma unroll
    for (int i = 0; i < 4; ++i)
#pragma unroll
        for (int e = 0; e < 4; ++e) {
            float pm = fmaxf(fmaxf(acc[i][0][e], acc[i][1][e]), fmaxf(acc[i][2][e], acc[i][3][e]));
#pragma unroll
            for (int off = 1; off < 16; off <<= 1) pm = fmaxf(pm, __shfl_xor(pm, off));
            if (r == 0) wmax[w][i * 16 + g * 4 + e] = pm;
        }
    __syncthreads();
#pragma unroll
    for (int i = 0; i < 4; ++i)
#pragma unroll
        for (int e = 0; e < 4; ++e) {
            int row = i * 16 + g * 4 + e;
            float rm = fmaxf(fmaxf(wmax[0][row], wmax[1][row]), fmaxf(wmax[2][row], wmax[3][row]));
            float dg = diag[row];
#pragma unroll
            for (int j = 0; j < 4; ++j) {
                float val = RATIO * (__expf(NORMALIZER * acc[i][j][e] - dg - NORMALIZER * rm) + EPSF);
                qp[(size_t)(h * NN + n0 + row) * MM + w * 64 + j * 16 + r] = f2bf(val);
            }
        }
}

// ---------------- K4: ctx partials: part[s][h][m][e] = sum_{n in slice} kp[n][m] v[n][e] ----
__global__ __launch_bounds__(256) void ctx_kernel(const u16* __restrict__ kp,
                                                  const void* __restrict__ v,
                                                  const int* __restrict__ mode_p,
                                                  float* __restrict__ cpart) {
    int mode = *mode_p;
    int h = blockIdx.x >> 4;
    int s = blockIdx.x & 15;
    int nb = s * 256;
    int tid = threadIdx.x, w = tid >> 6, lane = tid & 63, r = lane & 15, g = lane >> 4;
    f32x4 acc[4][4];
#pragma unroll
    for (int i = 0; i < 4; ++i)
#pragma unroll
        for (int j = 0; j < 4; ++j)
#pragma unroll
            for (int e = 0; e < 4; ++e) acc[i][j][e] = 0.f;
    const u16* kph = kp + (size_t)h * NN * MM;
    for (int nc = 0; nc < 256; nc += 32) {
        int n0 = nb + nc;
        bf16x8 a[4];  // A[m][n] = kp[n][m]: transposed gather
#pragma unroll
        for (int i = 0; i < 4; ++i)
#pragma unroll
            for (int jj = 0; jj < 8; ++jj)
                a[i][jj] = (short)kph[(size_t)(n0 + g * 8 + jj) * MM + w * 64 + i * 16 + r];
        bf16x8 bh[4], bl[4];
#pragma unroll
        for (int j = 0; j < 4; ++j) {
            float v8[8];
#pragma unroll
            for (int jj = 0; jj < 8; ++jj)
                v8[jj] = ldx(v, (size_t)(h * NN + n0 + g * 8 + jj) * DD + j * 16 + r, mode);
            split8(v8, bh[j], bl[j]);
        }
#pragma unroll
        for (int i = 0; i < 4; ++i)
#pragma unroll
            for (int j = 0; j < 4; ++j)
                acc[i][j] = __builtin_amdgcn_mfma_f32_16x16x32_bf16(a[i], bh[j], acc[i][j], 0, 0, 0);
        if (mode) {
#pragma unroll
            for (int i = 0; i < 4; ++i)
#pragma unroll
                for (int j = 0; j < 4; ++j)
                    acc[i][j] = __builtin_amdgcn_mfma_f32_16x16x32_bf16(a[i], bl[j], acc[i][j], 0, 0, 0);
        }
    }
    float* cp = cpart + (size_t)(s * HH + h) * MM * DD;
#pragma unroll
    for (int i = 0; i < 4; ++i)
#pragma unroll
        for (int j = 0; j < 4; ++j)
#pragma unroll
            for (int e = 0; e < 4; ++e)
                cp[(size_t)(w * 64 + i * 16 + g * 4 + e) * DD + j * 16 + r] = acc[i][j][e];
}

// ---------------- K4b: reduce 16 ctx partials ----------------
__global__ __launch_bounds__(256) void ctxred_kernel(const float* __restrict__ cpart,
                                                     float* __restrict__ ctx) {
    int idx = blockIdx.x * 256 + threadIdx.x;  // < 65536 float4
    const float4* cp4 = (const float4*)cpart;
    float4 s = cp4[idx];
#pragma unroll
    for (int p = 1; p < 16; ++p) {
        float4 t = cp4[(size_t)p * 65536 + idx];
        s.x += t.x; s.y += t.y; s.z += t.z; s.w += t.w;
    }
    ((float4*)ctx)[idx] = s;
}

// ---------------- K5: d_inv ----------------
__global__ __launch_bounds__(256) void dinv_kernel(const u16* __restrict__ qp,
                                                   const float* __restrict__ ksum,
                                                   float* __restrict__ dinv) {
    int gw = (int)((blockIdx.x * 256 + threadIdx.x) >> 6);
    int lane = threadIdx.x & 63;
    int h = gw >> 12;
    int n = gw & 4095;
    const u16* row = qp + (size_t)(h * NN + n) * MM;
    const float* ks = ksum + h * MM;
    float s = 0.f;
#pragma unroll
    for (int j = 0; j < 4; ++j) {
        int m = lane + 64 * j;
        s += bf2f(row[m]) * ks[m];
    }
    for (int off = 32; off; off >>= 1) s += __shfl_down(s, off);
    if (lane == 0) dinv[gw] = 1.0f / s;
}

// ---------------- K6: alignment out = (qp @ ctx) * dinv (MFMA) ----------------
__global__ __launch_bounds__(256) void out_kernel(const u16* __restrict__ qp,
                                                  const float* __restrict__ ctx,
                                                  const float* __restrict__ dinv,
                                                  const int* __restrict__ mode_p,
                                                  void* __restrict__ outv) {
    int mode = *mode_p;
    int h = blockIdx.x >> 5;
    int n0 = (blockIdx.x & 31) * 128;
    int tid = threadIdx.x, w = tid >> 6, lane = tid & 63, r = lane & 15, g = lane >> 4;
    int nw = n0 + w * 32;
    f32x4 acc[2][4];
#pragma unroll
    for (int i = 0; i < 2; ++i)
#pragma unroll
        for (int j = 0; j < 4; ++j)
#pragma unroll
            for (int e = 0; e < 4; ++e) acc[i][j][e] = 0.f;
    const u16* qph = qp + ((size_t)h * NN + nw) * MM;
    const float* ctxh = ctx + (size_t)h * MM * DD;
#pragma unroll
    for (int ks = 0; ks < 8; ++ks) {
        bf16x8 a[2];
#pragma unroll
        for (int i = 0; i < 2; ++i)
            a[i] = *(const bf16x8*)(qph + (size_t)(i * 16 + r) * MM + ks * 32 + g * 8);
        bf16x8 bh[4], bl[4];
#pragma unroll
        for (int j = 0; j < 4; ++j) {
            float v8[8];
#pragma unroll
            for (int jj = 0; jj < 8; ++jj)
                v8[jj] = ctxh[(size_t)(ks * 32 + g * 8 + jj) * DD + j * 16 + r];
            split8(v8, bh[j], bl[j]);
        }
#pragma unroll
        for (int i = 0; i < 2; ++i)
#pragma unroll
            for (int j = 0; j < 4; ++j) {
                acc[i][j] = __builtin_amdgcn_mfma_f32_16x16x32_bf16(a[i], bh[j], acc[i][j], 0, 0, 0);
                acc[i][j] = __builtin_amdgcn_mfma_f32_16x16x32_bf16(a[i], bl[j], acc[i][j], 0, 0, 0);
            }
    }
#pragma unroll
    for (int i = 0; i < 2; ++i)
#pragma unroll
        for (int e = 0; e < 4; ++e) {
            int n = nw + i * 16 + g * 4 + e;
            float di = dinv[h * NN + n];
            size_t ob = (size_t)(h * NN + n) * DD;
#pragma unroll
            for (int j = 0; j < 4; ++j) {
                float val = acc[i][j][e] * di;
                if (mode) ((float*)outv)[ob + j * 16 + r] = val;
                else ((u16*)outv)[ob + j * 16 + r] = f2bf(val);
            }
        }
}

// ---------------- K7: weights = qp @ kp^T per head (MFMA, XCD-swizzled) ----------------
__global__ __launch_bounds__(256) void weights_kernel(const u16* __restrict__ qp,
                                                      const u16* __restrict__ kp,
                                                      const int* __restrict__ mode_p,
                                                      void* __restrict__ woutv) {
    int mode = *mode_p;
    int bid0 = blockIdx.x;
    // bijective XCD swizzle: 16384 blocks = 8 XCDs x 2048; each XCD owns 2 heads
    int bid = ((bid0 & 7) << 11) + (bid0 >> 3);
    int h = bid >> 10;
    int t = bid & 1023;
    int qt = t >> 5, kt = t & 31;
    int tid = threadIdx.x;
    int w = tid >> 6, lane = tid & 63;
    int wq = w >> 1, wk = w & 1;
    int r = lane & 15, quad = lane >> 4;
    const u16* qh = qp + (size_t)h * NN * MM;
    const u16* kh = kp + (size_t)h * NN * MM;
    int qrow0 = qt * 128 + wq * 64;
    int krow0 = kt * 128 + wk * 64;
    f32x4 acc[4][4];
#pragma unroll
    for (int i = 0; i < 4; ++i)
#pragma unroll
        for (int j = 0; j < 4; ++j)
#pragma unroll
            for (int e = 0; e < 4; ++e) acc[i][j][e] = 0.f;
    for (int k0 = 0; k0 < 256; k0 += 32) {
        bf16x8 af[4], bfr[4];
#pragma unroll
        for (int i = 0; i < 4; ++i)
            af[i] = *(const bf16x8*)(qh + (size_t)(qrow0 + i * 16 + r) * MM + k0 + quad * 8);
#pragma unroll
        for (int j = 0; j < 4; ++j)
            bfr[j] = *(const bf16x8*)(kh + (size_t)(krow0 + j * 16 + r) * MM + k0 + quad * 8);
#pragma unroll
        for (int i = 0; i < 4; ++i)
#pragma unroll
            for (int j = 0; j < 4; ++j)
                acc[i][j] = __builtin_amdgcn_mfma_f32_16x16x32_bf16(af[i], bfr[j], acc[i][j], 0, 0, 0);
    }
    size_t wbase = 4194304 + (size_t)h * NN * NN;
    if (mode) {
        float* wout = (float*)woutv;
#pragma unroll
        for (int i = 0; i < 4; ++i)
#pragma unroll
            for (int j = 0; j < 4; ++j)
#pragma unroll
                for (int e = 0; e < 4; ++e) {
                    int qr = qrow0 + i * 16 + quad * 4 + e;
                    int kc = krow0 + j * 16 + r;
                    wout[wbase + (size_t)qr * NN + kc] = acc[i][j][e];
                }
    } else {
        u16* wout = (u16*)woutv;
#pragma unroll
        for (int i = 0; i < 4; ++i)
#pragma unroll
            for (int j = 0; j < 4; ++j)
#pragma unroll
                for (int e = 0; e < 4; ++e) {
                    int qr = qrow0 + i * 16 + quad * 4 + e;
                    int kc = krow0 + j * 16 + r;
                    wout[wbase + (size_t)qr * NN + kc] = f2bf(acc[i][j][e]);
                }
    }
}

extern "C" void kernel_launch(void* const* d_in, const int* in_sizes, int n_in,
                              void* d_out, int out_size, void* d_ws, size_t ws_size,
                              hipStream_t stream) {
    (void)in_sizes; (void)n_in; (void)out_size; (void)ws_size;
    const void* q = d_in[0];
    const void* k = d_in[1];
    const void* v = d_in[2];
    const void* proj = d_in[3];

    char* ws = (char*)d_ws;
    u16* kp = (u16*)ws;                                    // 32 MB
    u16* qp = (u16*)(ws + 33554432);                       // 32 MB
    float* ksum = (float*)(ws + 67108864);                 // 16 KB
    float* ctx = (float*)(ws + 67125248);                  // 1 MB
    u32* gmax = (u32*)(ws + 68173824);                     // 4 B (padded)
    float* dinv = (float*)(ws + 68174080);                 // 256 KB
    int* mode = (int*)(ws + 68436224);                     // 4 B

    // ctx partials live in the (not-yet-written) weights region of d_out:
    // weights start at 16.8 MB (f32) / 8.4 MB (bf16); 96 MB offset is safely inside,
    // fully overwritten by weights_kernel afterwards. 16 slices x 1 MB = 16.8 MB.
    float* cpart = (float*)((char*)d_out + 100663296);

    hipMemsetAsync(ws + 67108864, 0, 1065216, stream);  // ksum + ctx + gmax

    detect_kernel<<<1, 256, 0, stream>>>((const u32*)q, mode);
    kmax_kernel<<<1024, 256, 0, stream>>>(k, proj, mode, gmax);
    kp_kernel<<<1024, 256, 0, stream>>>(k, proj, mode, gmax, kp, ksum);
    qp_kernel<<<1024, 256, 0, stream>>>(q, proj, mode, qp);
    ctx_kernel<<<256, 256, 0, stream>>>(kp, v, mode, cpart);
    ctxred_kernel<<<256, 256, 0, stream>>>(cpart, ctx);
    dinv_kernel<<<16384, 256, 0, stream>>>(qp, ksum, dinv);
    out_kernel<<<512, 256, 0, stream>>>(qp, ctx, dinv, mode, d_out);
    weights_kernel<<<16384, 256, 0, stream>>>(qp, kp, mode, d_out);
}